// Round 15
// baseline (44.690 us; speedup 1.0000x reference)
//
#include <hip/hip_runtime.h>
#include <math.h>

#define BLOCK 256
#define NBLK  1024              // persistent grid: 4 blocks/CU x 256 CUs

typedef _Float16 half2v __attribute__((ext_vector_type(2)));
typedef _Float16 half4v __attribute__((ext_vector_type(4)));
typedef float    float4v __attribute__((ext_vector_type(4)));

__device__ __forceinline__ half2v cvt_pk_h2(float a, float b) {
    return __builtin_bit_cast(half2v, __builtin_amdgcn_cvt_pkrtz(a, b));
}

__device__ __forceinline__ half4v mk_h4(unsigned w0, unsigned w1) {
    uint2 u; u.x = w0; u.y = w1;
    return __builtin_bit_cast(half4v, u);
}

#define H4(x) {(_Float16)(x), (_Float16)(x), (_Float16)(x), (_Float16)(x)}

// Packed-fp16 tanh: odd poly t*p(t^2), deg-5 in s, fit on s in [0,9], clamp
// |x|<=3, endpoint lifted so saturated units land on exactly +-1.0.
__device__ __forceinline__ half4v tanh_pk4(half4v x) {
    const half4v c5 = H4(-3.71625e-05f);
    const half4v c4 = H4( 1.09648e-03f);
    const half4v c3 = H4(-1.288264e-02f);
    const half4v c2 = H4( 7.941906e-02f);
    const half4v c1 = H4(-3.0042735e-01f);
    const half4v c0 = H4( 9.9607644e-01f);
    const half4v hi = H4( 3.0f);
    const half4v lo = H4(-3.0f);
    half4v t = __builtin_elementwise_min(__builtin_elementwise_max(x, lo), hi);
    half4v s = t * t;
#if __has_builtin(__builtin_elementwise_fma)
    half4v p = __builtin_elementwise_fma(c5, s, c4);
    p = __builtin_elementwise_fma(p, s, c3);
    p = __builtin_elementwise_fma(p, s, c2);
    p = __builtin_elementwise_fma(p, s, c1);
    p = __builtin_elementwise_fma(p, s, c0);
#else
    half4v p = c5 * s + c4;
    p = p * s + c3;
    p = p * s + c2;
    p = p * s + c1;
    p = p * s + c0;
#endif
    return t * p;
}

__device__ __forceinline__ half4v pk4_from_f32(float a, float b, float c, float d) {
    half2v lo = cvt_pk_h2(a, b);
    half2v hi = cvt_pk_h2(c, d);
    return __builtin_shufflevector(lo, hi, 0, 1, 2, 3);
}

__device__ __forceinline__ half4v act4(float4v d) {
    return tanh_pk4(pk4_from_f32(d[0], d[1], d[2], d[3]));
}

// ---- DS-free cross-lane via v_permlane{16,32}_swap (pure VALU) ----
#if __has_builtin(__builtin_amdgcn_permlane16_swap) && __has_builtin(__builtin_amdgcn_permlane32_swap)
#define SWAP16X(XV_) ({ auto _r = __builtin_amdgcn_permlane16_swap((XV_), (XV_), false, false); \
                        (unsigned)(_r[0] ^ _r[1] ^ (XV_)); })
#define SWAP32X(XV_) ({ auto _r = __builtin_amdgcn_permlane32_swap((XV_), (XV_), false, false); \
                        (unsigned)(_r[0] ^ _r[1] ^ (XV_)); })
#else
#define SWAP16X(XV_) ((unsigned)__shfl((int)(XV_), lane ^ 16, 64))
#define SWAP32X(XV_) ((unsigned)__shfl((int)(XV_), lane ^ 32, 64))
#endif

// Pack the 3 forcing series into an interleaved float4 table in d_ws.
__global__ __launch_bounds__(BLOCK) void pack_forcings_kernel(
    const float* __restrict__ precp_s, const float* __restrict__ temp_s,
    const float* __restrict__ lday_s, float4* __restrict__ F, int T)
{
    int i = blockIdx.x * BLOCK + threadIdx.x;
    if (i < T) F[i] = make_float4(precp_s[i], temp_s[i], lday_s[i], 0.0f);
}

#define MFMA16(A, B, C) __builtin_amdgcn_mfma_f32_16x16x16f16((A), (B), (C), 0, 0, 0)

// Persistent grid-stride kernel, 2-stage software pipeline over 128-pt tiles:
//   issue raw loads(next) -> MLP(cur) -> PREP(next: gather+interp) -> FINISH(cur)
// Theory (r15): one-shot blocks execute in phase-locked generations; the fixed
// ~19us idle across r5-r14 is every generation serially paying the load chain.
// In-wave pipelining hides it (r2, the only grid-stride round, had 92% busy).
// All state in NAMED scalars, manual A/B double-buffer (r6: arrays -> LDS).
__global__ __launch_bounds__(BLOCK, 4) void exphydro_mfma_kernel(
    const float* __restrict__ t, const float* __restrict__ S_snow,
    const float* __restrict__ S_water,
    const float4* __restrict__ F,
    const float* __restrict__ etW1, const float* __restrict__ etb1,
    const float* __restrict__ etW2, const float* __restrict__ etb2,
    const float* __restrict__ etW3, const float* __restrict__ etb3,
    const float* __restrict__ qW1, const float* __restrict__ qb1,
    const float* __restrict__ qW2, const float* __restrict__ qb2,
    const float* __restrict__ qW3, const float* __restrict__ qb3,
    const float* __restrict__ pDf, const float* __restrict__ pTmax,
    const float* __restrict__ pTmin,
    float* __restrict__ out, int N, int T)
{
    const int lane = threadIdx.x & 63;
    const int hi   = lane >> 4;
    const int m    = lane & 15;
    const int wave = threadIdx.x >> 6;
    const int wid    = blockIdx.x * (BLOCK / 64) + wave;
    const int nwaves = gridDim.x * (BLOCK / 64);
    const int ntiles = (N + 127) >> 7;      // 128 points per tile

    // ---------- A-fragments (weights, transposed), fp16 ----------
    half4v A1et, A1q, A2et, A2q, A3et, A3q;
    float4v C2et, C2q, C3et, C3q;
    #pragma unroll
    for (int j = 0; j < 4; j++) {
        int k = 4 * hi + j;
        float w1e = (k < 3) ? etW1[k * 16 + m] : ((k == 3) ? etb1[m] : 0.0f);
        float w1q = (k < 2) ? qW1 [k * 16 + m] : ((k == 2) ? qb1 [m] : 0.0f);
        A1et[j] = (_Float16)w1e;
        A1q [j] = (_Float16)w1q;
        A2et[j] = (_Float16)etW2[k * 16 + m];
        A2q [j] = (_Float16)qW2 [k * 16 + m];
        A3et[j] = (_Float16)etW3[k];     // replicated over all rows m
        A3q [j] = (_Float16)qW3 [k];
        C2et[j] = etb2[4 * hi + j];
        C2q [j] = qb2 [4 * hi + j];
        C3et[j] = etb3[0];
        C3q [j] = qb3 [0];
    }

    const float Df   = pDf[0];
    const float Tmax = pTmax[0];
    const float Tmin = pTmin[0];
    const float tmaxf = (float)(T - 1);
    const int   imax  = T - 2;

    if (wid >= ntiles) return;

    // ---------- pipeline state, all NAMED ----------
    float ntv0A, nss0A, nsw0A, ntv1A, nss1A, nsw1A;   // raw loads, stage A
    float ntv0B, nss0B, nsw0B, ntv1B, nss1B, nsw1B;   // raw loads, stage B
    int   pA0, pA1, pB0, pB1;
    float ssA0, swA0, tpA0, prA0, ldA0, ssA1, swA1, tpA1, prA1, ldA1;
    float ssB0, swB0, tpB0, prB0, ldB0, ssB1, swB1, tpB1, prB1, ldB1;
    unsigned i01A0, i23A0, i01A1, i23A1;
    unsigned i01B0, i23B0, i01B1, i23B1;

#define LOADRAW(S, TILE) {                                                     \
        int b_  = (TILE) * 128 + lane;                                         \
        int c0_ = (b_ < N) ? b_ : (N - 1);                                     \
        int b1_ = b_ + 64;                                                     \
        int c1_ = (b1_ < N) ? b1_ : (N - 1);                                   \
        ntv0##S = t[c0_]; nss0##S = S_snow[c0_]; nsw0##S = S_water[c0_];       \
        ntv1##S = t[c1_]; nss1##S = S_snow[c1_]; nsw1##S = S_water[c1_];       \
    }

#define PREP1(TV, SSI, SWI, SSo, SWo, TPo, PRo, LDo, I01o, I23o) {             \
        float tc_ = fminf(fmaxf((TV), 0.0f), tmaxf);                           \
        int i0_ = (int)tc_;                                                    \
        i0_ = (i0_ > imax) ? imax : i0_;                                       \
        float fr_ = tc_ - (float)i0_;                                          \
        float4 f0_ = F[i0_];                                                   \
        float4 f1_ = F[i0_ + 1];                                               \
        PRo = fmaf(fr_, f1_.x - f0_.x, f0_.x);                                 \
        TPo = fmaf(fr_, f1_.y - f0_.y, f0_.y);                                 \
        LDo = fmaf(fr_, f1_.z - f0_.z, f0_.z);                                 \
        SSo = (SSI); SWo = (SWI);                                              \
        I01o = __builtin_bit_cast(unsigned, cvt_pk_h2(SSo, SWo));              \
        I23o = __builtin_bit_cast(unsigned, cvt_pk_h2(TPo, PRo));              \
    }

#define PREP(S, TILE) {                                                        \
        p##S##0 = (TILE) * 128 + lane;                                         \
        p##S##1 = p##S##0 + 64;                                                \
        PREP1(ntv0##S, nss0##S, nsw0##S, ss##S##0, sw##S##0, tp##S##0,         \
              pr##S##0, ld##S##0, i01##S##0, i23##S##0)                        \
        PREP1(ntv1##S, nss1##S, nsw1##S, ss##S##1, sw##S##1, tp##S##1,         \
              pr##S##1, ld##S##1, i01##S##1, i23##S##1)                        \
    }

    const float4v zero4 = {0.0f, 0.0f, 0.0f, 0.0f};

    // stage-major MLP for one 64-pt half (i01=(ss,sw), i23=(tp lo, pr hi)):
    // B1et = {ss,sw,tp,1}: w0 = j01, w1 = 1.0h<<16 | (j23 & 0xFFFF)
    // B1q  = {sw,pr,1,0}:  w0 = (j01>>16) | (j23 & 0xFFFF0000), w1 = 1.0h
#define MLP_SET(I01v, I23v, E0, E1, E2, E3, Q0, Q1, Q2, Q3)                    \
    float E0, E1, E2, E3, Q0, Q1, Q2, Q3;                                      \
    {                                                                          \
        unsigned j01_0 = I01v;                                                 \
        unsigned j23_0 = I23v;                                                 \
        unsigned j01_1 = SWAP16X(I01v);                                        \
        unsigned j23_1 = SWAP16X(I23v);                                        \
        unsigned j01_2 = SWAP32X(I01v);                                        \
        unsigned j23_2 = SWAP32X(I23v);                                        \
        unsigned j01_3 = SWAP16X(j01_2);                                       \
        unsigned j23_3 = SWAP16X(j23_2);                                       \
        float4v d1e0 = MFMA16(A1et, mk_h4(j01_0, 0x3C000000u | (j23_0 & 0xFFFFu)), zero4); \
        float4v d1q0 = MFMA16(A1q,  mk_h4((j01_0 >> 16) | (j23_0 & 0xFFFF0000u), 0x3C00u), zero4); \
        float4v d1e1 = MFMA16(A1et, mk_h4(j01_1, 0x3C000000u | (j23_1 & 0xFFFFu)), zero4); \
        float4v d1q1 = MFMA16(A1q,  mk_h4((j01_1 >> 16) | (j23_1 & 0xFFFF0000u), 0x3C00u), zero4); \
        float4v d1e2 = MFMA16(A1et, mk_h4(j01_2, 0x3C000000u | (j23_2 & 0xFFFFu)), zero4); \
        float4v d1q2 = MFMA16(A1q,  mk_h4((j01_2 >> 16) | (j23_2 & 0xFFFF0000u), 0x3C00u), zero4); \
        float4v d1e3 = MFMA16(A1et, mk_h4(j01_3, 0x3C000000u | (j23_3 & 0xFFFFu)), zero4); \
        float4v d1q3 = MFMA16(A1q,  mk_h4((j01_3 >> 16) | (j23_3 & 0xFFFF0000u), 0x3C00u), zero4); \
        half4v b2e0 = act4(d1e0);  half4v b2q0 = act4(d1q0);                   \
        half4v b2e1 = act4(d1e1);  half4v b2q1 = act4(d1q1);                   \
        half4v b2e2 = act4(d1e2);  half4v b2q2 = act4(d1q2);                   \
        half4v b2e3 = act4(d1e3);  half4v b2q3 = act4(d1q3);                   \
        float4v d2e0 = MFMA16(A2et, b2e0, C2et);  float4v d2q0 = MFMA16(A2q, b2q0, C2q); \
        float4v d2e1 = MFMA16(A2et, b2e1, C2et);  float4v d2q1 = MFMA16(A2q, b2q1, C2q); \
        float4v d2e2 = MFMA16(A2et, b2e2, C2et);  float4v d2q2 = MFMA16(A2q, b2q2, C2q); \
        float4v d2e3 = MFMA16(A2et, b2e3, C2et);  float4v d2q3 = MFMA16(A2q, b2q3, C2q); \
        half4v b3e0 = act4(d2e0);  half4v b3q0 = act4(d2q0);                   \
        half4v b3e1 = act4(d2e1);  half4v b3q1 = act4(d2q1);                   \
        half4v b3e2 = act4(d2e2);  half4v b3q2 = act4(d2q2);                   \
        half4v b3e3 = act4(d2e3);  half4v b3q3 = act4(d2q3);                   \
        float4v d3e0 = MFMA16(A3et, b3e0, C3et);  float4v d3q0 = MFMA16(A3q, b3q0, C3q); \
        float4v d3e1 = MFMA16(A3et, b3e1, C3et);  float4v d3q1 = MFMA16(A3q, b3q1, C3q); \
        float4v d3e2 = MFMA16(A3et, b3e2, C3et);  float4v d3q2 = MFMA16(A3q, b3q2, C3q); \
        float4v d3e3 = MFMA16(A3et, b3e3, C3et);  float4v d3q3 = MFMA16(A3q, b3q3, C3q); \
        E0 = d3e0[0]; E1 = d3e1[0]; E2 = d3e2[0]; E3 = d3e3[0];                \
        Q0 = d3q0[0]; Q1 = d3q1[0]; Q2 = d3q2[0]; Q3 = d3q3[0];                \
    }

#define FINISH_POINT(Pv, SSv, SWv, TPv, PRv, LDv, E0, E1, E2, E3, Q0, Q1, Q2, Q3) \
    {                                                                          \
        float e01s = (lane & 16) ? E1 : E0;                                    \
        float e23s = (lane & 16) ? E3 : E2;                                    \
        float ET   = (lane & 32) ? e23s : e01s;                                \
        float q01s = (lane & 16) ? Q1 : Q0;                                    \
        float q23s = (lane & 16) ? Q3 : Q2;                                    \
        float Q    = (lane & 32) ? q23s : q01s;                                \
        float dT = TPv - Tmax;                                                 \
        half4v sargs = pk4_from_f32(5.0f * dT, 5.0f * SSv,                     \
                                    5.0f * (Tmin - TPv), 5.0f * SWv);          \
        half4v th = tanh_pk4(sargs);                                           \
        float stepA  = fmaf(0.5f, (float)th[0], 0.5f);                         \
        float stepSn = fmaf(0.5f, (float)th[1], 0.5f);                         \
        float stepPs = fmaf(0.5f, (float)th[2], 0.5f);                         \
        float sw01   = fmaf(0.5f, (float)th[3], 0.5f);                         \
        float melt = stepA * stepSn * fminf(SSv, Df * dT);                     \
        float Ps   = stepPs * PRv;                                             \
        float Pr   = (1.0f - stepPs) * PRv;                                    \
        float dS1 = Ps - melt;                                                 \
        float dS2 = Pr + melt - sw01 * (LDv * __expf(ET) + __expf(Q));         \
        if (Pv < N) {                                                          \
            out[Pv]     = dS1;                                                 \
            out[N + Pv] = dS2;                                                 \
        }                                                                      \
    }

    // one pipeline half-iteration: CUR computed, NXT staged
#define HALF_ITER(CUR, NXT, NTC)                                               \
    LOADRAW(NXT, NTC)                                                          \
    MLP_SET(i01##CUR##0, i23##CUR##0, e0##CUR, e1##CUR, e2##CUR, e3##CUR,      \
            g0##CUR, g1##CUR, g2##CUR, g3##CUR)                                \
    MLP_SET(i01##CUR##1, i23##CUR##1, f0##CUR, f1##CUR, f2##CUR, f3##CUR,      \
            h0##CUR, h1##CUR, h2##CUR, h3##CUR)                                \
    PREP(NXT, NTC)                                                             \
    FINISH_POINT(p##CUR##0, ss##CUR##0, sw##CUR##0, tp##CUR##0, pr##CUR##0,    \
                 ld##CUR##0, e0##CUR, e1##CUR, e2##CUR, e3##CUR,               \
                 g0##CUR, g1##CUR, g2##CUR, g3##CUR)                           \
    FINISH_POINT(p##CUR##1, ss##CUR##1, sw##CUR##1, tp##CUR##1, pr##CUR##1,    \
                 ld##CUR##1, f0##CUR, f1##CUR, f2##CUR, f3##CUR,               \
                 h0##CUR, h1##CUR, h2##CUR, h3##CUR)

    // ---------- prologue ----------
    LOADRAW(A, wid)
    PREP(A, wid)
    int nxt = wid + nwaves;

    for (;;) {
        {
            int  ntc  = (nxt < ntiles) ? nxt : wid;   // clamped: harmless reload
            bool last = (nxt >= ntiles);
            HALF_ITER(A, B, ntc)
            if (last) return;
            nxt += nwaves;
        }
        {
            int  ntc  = (nxt < ntiles) ? nxt : wid;
            bool last = (nxt >= ntiles);
            HALF_ITER(B, A, ntc)
            if (last) return;
            nxt += nwaves;
        }
    }
}

extern "C" void kernel_launch(void* const* d_in, const int* in_sizes, int n_in,
                              void* d_out, int out_size, void* d_ws, size_t ws_size,
                              hipStream_t stream) {
    const float* t        = (const float*)d_in[0];
    const float* S_snow   = (const float*)d_in[1];
    const float* S_water  = (const float*)d_in[2];
    const float* precp_s  = (const float*)d_in[4];
    const float* temp_s   = (const float*)d_in[5];
    const float* lday_s   = (const float*)d_in[6];
    const float* etW1     = (const float*)d_in[7];
    const float* etb1     = (const float*)d_in[8];
    const float* etW2     = (const float*)d_in[9];
    const float* etb2     = (const float*)d_in[10];
    const float* etW3     = (const float*)d_in[11];
    const float* etb3     = (const float*)d_in[12];
    const float* qW1      = (const float*)d_in[13];
    const float* qb1      = (const float*)d_in[14];
    const float* qW2      = (const float*)d_in[15];
    const float* qb2      = (const float*)d_in[16];
    const float* qW3      = (const float*)d_in[17];
    const float* qb3      = (const float*)d_in[18];
    const float* pDf      = (const float*)d_in[19];
    const float* pTmax    = (const float*)d_in[20];
    const float* pTmin    = (const float*)d_in[21];

    int N = in_sizes[0];
    int T = in_sizes[3];
    float* out = (float*)d_out;
    float4* F = (float4*)d_ws;   // T*16 bytes, fits ws

    pack_forcings_kernel<<<(T + BLOCK - 1) / BLOCK, BLOCK, 0, stream>>>(
        precp_s, temp_s, lday_s, F, T);

    exphydro_mfma_kernel<<<NBLK, BLOCK, 0, stream>>>(
        t, S_snow, S_water, F,
        etW1, etb1, etW2, etb2, etW3, etb3,
        qW1, qb1, qW2, qb2, qW3, qb3,
        pDf, pTmax, pTmin, out, N, T);
}

// Round 16
// 39.893 us; speedup vs baseline: 1.1202x; 1.1202x over previous
//
#include <hip/hip_runtime.h>
#include <math.h>

#define BLOCK 256
#define PPT   2                 // points per thread (hand-unrolled, NO arrays)

typedef _Float16 half2v __attribute__((ext_vector_type(2)));
typedef _Float16 half4v __attribute__((ext_vector_type(4)));
typedef float    float4v __attribute__((ext_vector_type(4)));

__device__ __forceinline__ half2v cvt_pk_h2(float a, float b) {
    return __builtin_bit_cast(half2v, __builtin_amdgcn_cvt_pkrtz(a, b));
}

__device__ __forceinline__ half4v mk_h4(unsigned w0, unsigned w1) {
    uint2 u; u.x = w0; u.y = w1;
    return __builtin_bit_cast(half4v, u);
}

#define H4(x) {(_Float16)(x), (_Float16)(x), (_Float16)(x), (_Float16)(x)}

// Packed-fp16 tanh: odd poly t*p(t^2), DEG-4 in s (r16: one fma fewer than the
// deg-5), Chebyshev-node interp on s in [0,9], clamp |x|<=3, endpoint pinned
// p(9)=1/3 so saturated units land on +-1.0 (to 4e-5). Fit err ~5e-3.
__device__ __forceinline__ half4v tanh_pk4(half4v x) {
    const half4v c4 = H4( 2.6825e-04f);
    const half4v c3 = H4(-6.6518e-03f);
    const half4v c2 = H4( 6.2069e-02f);
    const half4v c1 = H4(-2.89456e-01f);
    const half4v c0 = H4( 1.0f);
    const half4v hi = H4( 3.0f);
    const half4v lo = H4(-3.0f);
    half4v t = __builtin_elementwise_min(__builtin_elementwise_max(x, lo), hi);
    half4v s = t * t;
#if __has_builtin(__builtin_elementwise_fma)
    half4v p = __builtin_elementwise_fma(c4, s, c3);
    p = __builtin_elementwise_fma(p, s, c2);
    p = __builtin_elementwise_fma(p, s, c1);
    p = __builtin_elementwise_fma(p, s, c0);
#else
    half4v p = c4 * s + c3;
    p = p * s + c2;
    p = p * s + c1;
    p = p * s + c0;
#endif
    return t * p;
}

__device__ __forceinline__ half4v pk4_from_f32(float a, float b, float c, float d) {
    half2v lo = cvt_pk_h2(a, b);
    half2v hi = cvt_pk_h2(c, d);
    return __builtin_shufflevector(lo, hi, 0, 1, 2, 3);
}

__device__ __forceinline__ half4v act4(float4v d) {
    return tanh_pk4(pk4_from_f32(d[0], d[1], d[2], d[3]));
}

// ---- DS-free cross-lane via v_permlane{16,32}_swap (pure VALU) ----
#if __has_builtin(__builtin_amdgcn_permlane16_swap) && __has_builtin(__builtin_amdgcn_permlane32_swap)
#define SWAP16X(XV_) ({ auto _r = __builtin_amdgcn_permlane16_swap((XV_), (XV_), false, false); \
                        (unsigned)(_r[0] ^ _r[1] ^ (XV_)); })
#define SWAP32X(XV_) ({ auto _r = __builtin_amdgcn_permlane32_swap((XV_), (XV_), false, false); \
                        (unsigned)(_r[0] ^ _r[1] ^ (XV_)); })
#else
#define SWAP16X(XV_) ((unsigned)__shfl((int)(XV_), lane ^ 16, 64))
#define SWAP32X(XV_) ((unsigned)__shfl((int)(XV_), lane ^ 32, 64))
#endif

// Pack the 3 forcing series into an interleaved float4 table in d_ws.
__global__ __launch_bounds__(BLOCK) void pack_forcings_kernel(
    const float* __restrict__ precp_s, const float* __restrict__ temp_s,
    const float* __restrict__ lday_s, float4* __restrict__ F, int T)
{
    int i = blockIdx.x * BLOCK + threadIdx.x;
    if (i < T) F[i] = make_float4(precp_s[i], temp_s[i], lday_s[i], 0.0f);
}

#define MFMA16(A, B, C) __builtin_amdgcn_mfma_f32_16x16x16f16((A), (B), (C), 0, 0, 0)

// MFMA 16x16x16 f16, swapped orientation: D = W^T . X  (cols = points).
// Shuffle-free layer chaining; layer-3 weights replicated -> cndmask pickup.
// PPT=2 stage-major, NAMED scalars only, zero DS ops.
// r16: deg-4 act poly, v_perm B1-builds, EXACT template elides bounds checks
// (grid covers N exactly: 2^21 = 4096 blk x 512 pts).
template<bool EXACT>
__global__ __launch_bounds__(BLOCK, 4) void exphydro_mfma_kernel(
    const float* __restrict__ t, const float* __restrict__ S_snow,
    const float* __restrict__ S_water,
    const float4* __restrict__ F,
    const float* __restrict__ etW1, const float* __restrict__ etb1,
    const float* __restrict__ etW2, const float* __restrict__ etb2,
    const float* __restrict__ etW3, const float* __restrict__ etb3,
    const float* __restrict__ qW1, const float* __restrict__ qb1,
    const float* __restrict__ qW2, const float* __restrict__ qb2,
    const float* __restrict__ qW3, const float* __restrict__ qb3,
    const float* __restrict__ pDf, const float* __restrict__ pTmax,
    const float* __restrict__ pTmin,
    float* __restrict__ out, int N, int T)
{
    const int lane = threadIdx.x & 63;
    const int hi   = lane >> 4;
    const int m    = lane & 15;
    const int wave = threadIdx.x >> 6;
    const int base = blockIdx.x * (BLOCK * PPT) + wave * (64 * PPT);

    // ---------- A-fragments (weights, transposed), fp16 ----------
    half4v A1et, A1q, A2et, A2q, A3et, A3q;
    float4v C2et, C2q, C3et, C3q;
    #pragma unroll
    for (int j = 0; j < 4; j++) {
        int k = 4 * hi + j;
        float w1e = (k < 3) ? etW1[k * 16 + m] : ((k == 3) ? etb1[m] : 0.0f);
        float w1q = (k < 2) ? qW1 [k * 16 + m] : ((k == 2) ? qb1 [m] : 0.0f);
        A1et[j] = (_Float16)w1e;
        A1q [j] = (_Float16)w1q;
        A2et[j] = (_Float16)etW2[k * 16 + m];
        A2q [j] = (_Float16)qW2 [k * 16 + m];
        A3et[j] = (_Float16)etW3[k];     // replicated over all rows m
        A3q [j] = (_Float16)qW3 [k];
        C2et[j] = etb2[4 * hi + j];
        C2q [j] = qb2 [4 * hi + j];
        C3et[j] = etb3[0];
        C3q [j] = qb3 [0];
    }

    const float Df   = pDf[0];
    const float Tmax = pTmax[0];
    const float Tmin = pTmin[0];
    const float tmaxf = (float)(T - 1);
    const int   imax  = T - 2;
    const unsigned kONE = 0x3C000000u;   // 1.0h in byte lanes 2-3 (for v_perm)

    // ---------- per-point loads + interp, NAMED scalars ----------
    // i01 = (ss lo, sw hi); i23 = (tp lo, pr hi)
#define LOAD_POINT(U, Pv, SSv, SWv, TPv, PRv, LDv, I01v, I23v)                 \
    const int Pv = base + (U) * 64 + lane;                                     \
    float SSv, SWv, TPv, PRv, LDv; unsigned I01v, I23v;                        \
    {                                                                          \
        int pc = EXACT ? Pv : ((Pv < N) ? Pv : (N - 1));                       \
        float tv = t[pc];                                                      \
        SSv = S_snow[pc];                                                      \
        SWv = S_water[pc];                                                     \
        float tc = fminf(fmaxf(tv, 0.0f), tmaxf);                              \
        int i0 = (int)tc;                                                      \
        i0 = (i0 > imax) ? imax : i0;                                          \
        float fr = tc - (float)i0;                                             \
        float4 f0 = F[i0];                                                     \
        float4 f1 = F[i0 + 1];                                                 \
        PRv = fmaf(fr, f1.x - f0.x, f0.x);                                     \
        TPv = fmaf(fr, f1.y - f0.y, f0.y);                                     \
        LDv = fmaf(fr, f1.z - f0.z, f0.z);                                     \
        I01v = __builtin_bit_cast(unsigned, cvt_pk_h2(SSv, SWv));              \
        I23v = __builtin_bit_cast(unsigned, cvt_pk_h2(TPv, PRv));              \
    }

    LOAD_POINT(0, p0, ss0, sw0, tp0, pr0, ld0, i01_0, i23_0)
    LOAD_POINT(1, p1, ss1, sw1, tp1, pr1, ld1, i01_1, i23_1)

    const float4v zero4 = {0.0f, 0.0f, 0.0f, 0.0f};

    // B1et = {ss,sw,tp,1}: w0 = j01, w1 = perm(kONE, j23, [j23.b0,j23.b1,K.b2,K.b3])
    // B1q  = {sw,pr,1,0}:  w0 = perm(j23, j01, [j01.b2,j01.b3,j23.b2,j23.b3]), w1 = 1.0h
#define B1ET_W1(J23) __builtin_amdgcn_perm(kONE, (J23), 0x07060100u)
#define B1Q_W0(J01, J23) __builtin_amdgcn_perm((J23), (J01), 0x07060302u)

    // ---------- stage-major MLP for one point-set (4 groups breadth-first) ----
#define MLP_SET(I01v, I23v, E0, E1, E2, E3, Q0, Q1, Q2, Q3)                    \
    float E0, E1, E2, E3, Q0, Q1, Q2, Q3;                                      \
    {                                                                          \
        unsigned j01_0 = I01v;                                                 \
        unsigned j23_0 = I23v;                                                 \
        unsigned j01_1 = SWAP16X(I01v);                                        \
        unsigned j23_1 = SWAP16X(I23v);                                        \
        unsigned j01_2 = SWAP32X(I01v);                                        \
        unsigned j23_2 = SWAP32X(I23v);                                        \
        unsigned j01_3 = SWAP16X(j01_2);                                       \
        unsigned j23_3 = SWAP16X(j23_2);                                       \
        float4v d1e0 = MFMA16(A1et, mk_h4(j01_0, B1ET_W1(j23_0)), zero4);      \
        float4v d1q0 = MFMA16(A1q,  mk_h4(B1Q_W0(j01_0, j23_0), 0x3C00u), zero4); \
        float4v d1e1 = MFMA16(A1et, mk_h4(j01_1, B1ET_W1(j23_1)), zero4);      \
        float4v d1q1 = MFMA16(A1q,  mk_h4(B1Q_W0(j01_1, j23_1), 0x3C00u), zero4); \
        float4v d1e2 = MFMA16(A1et, mk_h4(j01_2, B1ET_W1(j23_2)), zero4);      \
        float4v d1q2 = MFMA16(A1q,  mk_h4(B1Q_W0(j01_2, j23_2), 0x3C00u), zero4); \
        float4v d1e3 = MFMA16(A1et, mk_h4(j01_3, B1ET_W1(j23_3)), zero4);      \
        float4v d1q3 = MFMA16(A1q,  mk_h4(B1Q_W0(j01_3, j23_3), 0x3C00u), zero4); \
        half4v b2e0 = act4(d1e0);  half4v b2q0 = act4(d1q0);                   \
        half4v b2e1 = act4(d1e1);  half4v b2q1 = act4(d1q1);                   \
        half4v b2e2 = act4(d1e2);  half4v b2q2 = act4(d1q2);                   \
        half4v b2e3 = act4(d1e3);  half4v b2q3 = act4(d1q3);                   \
        float4v d2e0 = MFMA16(A2et, b2e0, C2et);  float4v d2q0 = MFMA16(A2q, b2q0, C2q); \
        float4v d2e1 = MFMA16(A2et, b2e1, C2et);  float4v d2q1 = MFMA16(A2q, b2q1, C2q); \
        float4v d2e2 = MFMA16(A2et, b2e2, C2et);  float4v d2q2 = MFMA16(A2q, b2q2, C2q); \
        float4v d2e3 = MFMA16(A2et, b2e3, C2et);  float4v d2q3 = MFMA16(A2q, b2q3, C2q); \
        half4v b3e0 = act4(d2e0);  half4v b3q0 = act4(d2q0);                   \
        half4v b3e1 = act4(d2e1);  half4v b3q1 = act4(d2q1);                   \
        half4v b3e2 = act4(d2e2);  half4v b3q2 = act4(d2q2);                   \
        half4v b3e3 = act4(d2e3);  half4v b3q3 = act4(d2q3);                   \
        float4v d3e0 = MFMA16(A3et, b3e0, C3et);  float4v d3q0 = MFMA16(A3q, b3q0, C3q); \
        float4v d3e1 = MFMA16(A3et, b3e1, C3et);  float4v d3q1 = MFMA16(A3q, b3q1, C3q); \
        float4v d3e2 = MFMA16(A3et, b3e2, C3et);  float4v d3q2 = MFMA16(A3q, b3q2, C3q); \
        float4v d3e3 = MFMA16(A3et, b3e3, C3et);  float4v d3q3 = MFMA16(A3q, b3q3, C3q); \
        E0 = d3e0[0]; E1 = d3e1[0]; E2 = d3e2[0]; E3 = d3e3[0];                \
        Q0 = d3q0[0]; Q1 = d3q1[0]; Q2 = d3q2[0]; Q3 = d3q3[0];                \
    }

    MLP_SET(i01_0, i23_0, et00, et01, et02, et03, q00, q01, q02, q03)
    MLP_SET(i01_1, i23_1, et10, et11, et12, et13, q10, q11, q12, q13)

    // ---------- pickup + physics + store ----------
#define FINISH_POINT(Pv, SSv, SWv, TPv, PRv, LDv, E0, E1, E2, E3, Q0, Q1, Q2, Q3) \
    {                                                                          \
        float e01s = (lane & 16) ? E1 : E0;                                    \
        float e23s = (lane & 16) ? E3 : E2;                                    \
        float ET   = (lane & 32) ? e23s : e01s;                                \
        float q01s = (lane & 16) ? Q1 : Q0;                                    \
        float q23s = (lane & 16) ? Q3 : Q2;                                    \
        float Q    = (lane & 32) ? q23s : q01s;                                \
        float dT = TPv - Tmax;                                                 \
        half4v sargs = pk4_from_f32(5.0f * dT, 5.0f * SSv,                     \
                                    5.0f * (Tmin - TPv), 5.0f * SWv);          \
        half4v th = tanh_pk4(sargs);                                           \
        float stepA  = fmaf(0.5f, (float)th[0], 0.5f);                         \
        float stepSn = fmaf(0.5f, (float)th[1], 0.5f);                         \
        float stepPs = fmaf(0.5f, (float)th[2], 0.5f);                         \
        float sw01   = fmaf(0.5f, (float)th[3], 0.5f);                         \
        float melt = stepA * stepSn * fminf(SSv, Df * dT);                     \
        float Ps   = stepPs * PRv;                                             \
        float Pr   = (1.0f - stepPs) * PRv;                                    \
        float dS1 = Ps - melt;                                                 \
        float dS2 = Pr + melt - sw01 * (LDv * __expf(ET) + __expf(Q));         \
        if (EXACT || Pv < N) {                                                 \
            out[Pv]     = dS1;                                                 \
            out[N + Pv] = dS2;                                                 \
        }                                                                      \
    }

    FINISH_POINT(p0, ss0, sw0, tp0, pr0, ld0, et00, et01, et02, et03, q00, q01, q02, q03)
    FINISH_POINT(p1, ss1, sw1, tp1, pr1, ld1, et10, et11, et12, et13, q10, q11, q12, q13)
}

extern "C" void kernel_launch(void* const* d_in, const int* in_sizes, int n_in,
                              void* d_out, int out_size, void* d_ws, size_t ws_size,
                              hipStream_t stream) {
    const float* t        = (const float*)d_in[0];
    const float* S_snow   = (const float*)d_in[1];
    const float* S_water  = (const float*)d_in[2];
    const float* precp_s  = (const float*)d_in[4];
    const float* temp_s   = (const float*)d_in[5];
    const float* lday_s   = (const float*)d_in[6];
    const float* etW1     = (const float*)d_in[7];
    const float* etb1     = (const float*)d_in[8];
    const float* etW2     = (const float*)d_in[9];
    const float* etb2     = (const float*)d_in[10];
    const float* etW3     = (const float*)d_in[11];
    const float* etb3     = (const float*)d_in[12];
    const float* qW1      = (const float*)d_in[13];
    const float* qb1      = (const float*)d_in[14];
    const float* qW2      = (const float*)d_in[15];
    const float* qb2      = (const float*)d_in[16];
    const float* qW3      = (const float*)d_in[17];
    const float* qb3      = (const float*)d_in[18];
    const float* pDf      = (const float*)d_in[19];
    const float* pTmax    = (const float*)d_in[20];
    const float* pTmin    = (const float*)d_in[21];

    int N = in_sizes[0];
    int T = in_sizes[3];
    float* out = (float*)d_out;
    float4* F = (float4*)d_ws;   // T*16 bytes, fits ws

    pack_forcings_kernel<<<(T + BLOCK - 1) / BLOCK, BLOCK, 0, stream>>>(
        precp_s, temp_s, lday_s, F, T);

    int per_block = BLOCK * PPT;
    int nblk = (N + per_block - 1) / per_block;
    if (nblk * per_block == N) {
        exphydro_mfma_kernel<true><<<nblk, BLOCK, 0, stream>>>(
            t, S_snow, S_water, F,
            etW1, etb1, etW2, etb2, etW3, etb3,
            qW1, qb1, qW2, qb2, qW3, qb3,
            pDf, pTmax, pTmin, out, N, T);
    } else {
        exphydro_mfma_kernel<false><<<nblk, BLOCK, 0, stream>>>(
            t, S_snow, S_water, F,
            etW1, etb1, etW2, etb2, etW3, etb3,
            qW1, qb1, qW2, qb2, qW3, qb3,
            pDf, pTmax, pTmin, out, N, T);
    }
}